// Round 4
// baseline (233.073 us; speedup 1.0000x reference)
//
#include <hip/hip_runtime.h>

#define NUM 16
#define TPB 256
#define TRK_PER_THREAD 2

typedef float v4f __attribute__((ext_vector_type(4)));  // native vec for nontemporal builtins

// One thread per 2 adjacent (batch,track) pairs. No LDS, no barriers: all
// global loads for both tracks are issued up front (~11 outstanding vmem ops
// per thread) to maximize memory-level parallelism. P loads / rP stores are
// nontemporal (streamed once, no reuse).
__global__ __launch_bounds__(TPB) void kf_update_kernel(
    const float* __restrict__ value,   // (B, 32)
    const float* __restrict__ vel,     // (B, 32)
    const float* __restrict__ Pin,     // (B, 16, 4, 4)
    const float* __restrict__ obs,     // (B, 32)
    const int*   __restrict__ lm,      // (B, 16)
    const int*   __restrict__ mask,    // (B, 16)
    float* __restrict__ out,           // rv(B*32) | rm(B*16) | rvel(B*32) | rP(B*256)
    int Bn)
{
    const int gtid  = blockIdx.x * TPB + threadIdx.x;  // pair index
    const int total = Bn * NUM;                        // track count
    if (gtid * TRK_PER_THREAD >= total) return;

    // ---- issue ALL loads up front ----
    const float4 vv = reinterpret_cast<const float4*>(value)[gtid]; // trk0:(x,y) trk1:(z,w)
    const float4 uu = reinterpret_cast<const float4*>(vel)[gtid];
    const float4 oo = reinterpret_cast<const float4*>(obs)[gtid];
    const int2   ll = reinterpret_cast<const int2*>(lm)[gtid];
    const int2   mm = reinterpret_cast<const int2*>(mask)[gtid];

    float Pm[TRK_PER_THREAD][16];
    {
        const v4f* Pg = reinterpret_cast<const v4f*>(Pin) + (size_t)gtid * 8;
        #pragma unroll
        for (int c = 0; c < 8; ++c) {
            const v4f x = __builtin_nontemporal_load(Pg + c);
            Pm[c >> 2][(c & 3) * 4 + 0] = x.x;
            Pm[c >> 2][(c & 3) * 4 + 1] = x.y;
            Pm[c >> 2][(c & 3) * 4 + 2] = x.z;
            Pm[c >> 2][(c & 3) * 4 + 3] = x.w;
        }
    }

    float rv[TRK_PER_THREAD][2], rvl[TRK_PER_THREAD][2], rmv[TRK_PER_THREAD];
    float rP[TRK_PER_THREAD][16];

    #pragma unroll
    for (int t = 0; t < TRK_PER_THREAD; ++t) {
        const float vx = (t == 0) ? vv.x : vv.z;
        const float vy = (t == 0) ? vv.y : vv.w;
        const float ux = (t == 0) ? uu.x : uu.z;
        const float uy = (t == 0) ? uu.y : uu.w;
        const float ox = (t == 0) ? oo.x : oo.z;
        const float oy = (t == 0) ? oo.y : oo.w;
        const int   l  = (t == 0) ? ll.x : ll.y;
        const int   m  = (t == 0) ? mm.x : mm.y;
        const float* P = Pm[t];

        // predict
        const float p0 = vx + ux;
        const float p1 = vy + uy;
        const float p2 = ux;
        const float p3 = uy;

        // pP = F P F^T (row adds then col adds)
        float Q[4][4];
        #pragma unroll
        for (int j = 0; j < 4; ++j) {
            Q[0][j] = P[0 * 4 + j] + P[2 * 4 + j];
            Q[1][j] = P[1 * 4 + j] + P[3 * 4 + j];
            Q[2][j] = P[2 * 4 + j];
            Q[3][j] = P[3 * 4 + j];
        }
        float pP[4][4];
        #pragma unroll
        for (int i = 0; i < 4; ++i) {
            pP[i][0] = Q[i][0] + Q[i][2];
            pP[i][1] = Q[i][1] + Q[i][3];
            pP[i][2] = Q[i][2];
            pP[i][3] = Q[i][3];
        }

        // S = pP[:2,:2] + 1e-5 I; closed-form 2x2 inverse
        const float S00 = pP[0][0] + 1e-5f;
        const float S01 = pP[0][1];
        const float S10 = pP[1][0];
        const float S11 = pP[1][1] + 1e-5f;
        const float rdet = 1.0f / (S00 * S11 - S01 * S10);

        // K = pP[:, :2] @ Sinv
        float K0[4], K1[4];
        #pragma unroll
        for (int i = 0; i < 4; ++i) {
            K0[i] = (pP[i][0] * S11 - pP[i][1] * S10) * rdet;
            K1[i] = (pP[i][1] * S00 - pP[i][0] * S01) * rdet;
        }

        // state update
        const float y0 = ox - p0;
        const float y1 = oy - p1;
        const float upd0 = p0 + K0[0] * y0 + K1[0] * y1;
        const float upd1 = p1 + K0[1] * y0 + K1[1] * y1;
        const float upd2 = p2 + K0[2] * y0 + K1[2] * y1;
        const float upd3 = p3 + K0[3] * y0 + K1[3] * y1;

        // condition table
        const bool c1  = (l == 0) && (m == 0);
        const bool c2  = (l == 0) && (m != 0);
        const bool c3  = (l != 0) && (m == 0);
        const bool c4  = (l != 0) && (m != 0);
        const bool c3a = c3 && (l <= 5);

        rv[t][0]  = c4 ? upd0 : (c3 ? p0 : ox);
        rv[t][1]  = c4 ? upd1 : (c3 ? p1 : oy);
        rvl[t][0] = c4 ? upd2 : (c3a ? p2 : 0.0f);
        rvl[t][1] = c4 ? upd3 : (c3a ? p3 : 0.0f);
        rmv[t]    = (c2 || c4) ? 1.0f : (c3a ? (float)(l + 1) : 0.0f);

        // rP = select(c1: diag, c3a: pP, c4: pP - K pP[:2,:], else 0)
        #pragma unroll
        for (int i = 0; i < 4; ++i) {
            #pragma unroll
            for (int j = 0; j < 4; ++j) {
                const float Pn   = pP[i][j] - (K0[i] * pP[0][j] + K1[i] * pP[1][j]);
                const float diag = (i == j) ? ((i < 2) ? 1.0f : 10.0f) : 0.0f;
                rP[t][i * 4 + j] = c1 ? diag : (c3a ? pP[i][j] : (c4 ? Pn : 0.0f));
            }
        }
    }

    // ---- stores ----
    float* rv_out   = out;
    float* rm_out   = out + (size_t)Bn * 32;
    float* rvel_out = out + (size_t)Bn * 48;
    float* rP_out   = out + (size_t)Bn * 80;

    reinterpret_cast<float4*>(rv_out)[gtid] =
        make_float4(rv[0][0], rv[0][1], rv[1][0], rv[1][1]);
    reinterpret_cast<float2*>(rm_out)[gtid] = make_float2(rmv[0], rmv[1]);
    reinterpret_cast<float4*>(rvel_out)[gtid] =
        make_float4(rvl[0][0], rvl[0][1], rvl[1][0], rvl[1][1]);

    v4f* rPg = reinterpret_cast<v4f*>(rP_out) + (size_t)gtid * 8;
    #pragma unroll
    for (int c = 0; c < 8; ++c) {
        const float* s = &rP[c >> 2][(c & 3) * 4];
        v4f w; w.x = s[0]; w.y = s[1]; w.z = s[2]; w.w = s[3];
        __builtin_nontemporal_store(w, rPg + c);
    }
}

extern "C" void kernel_launch(void* const* d_in, const int* in_sizes, int n_in,
                              void* d_out, int out_size, void* d_ws, size_t ws_size,
                              hipStream_t stream) {
    const float* value = (const float*)d_in[0];
    const float* vel   = (const float*)d_in[1];
    const float* P     = (const float*)d_in[2];
    const float* obs   = (const float*)d_in[3];
    const int*   lm    = (const int*)d_in[4];
    const int*   mask  = (const int*)d_in[5];

    const int Bn    = in_sizes[0] / (2 * NUM);   // value is (B, 2*NUM)
    const int total = Bn * NUM;
    const int pairs = (total + TRK_PER_THREAD - 1) / TRK_PER_THREAD;
    const int blocks = (pairs + TPB - 1) / TPB;

    kf_update_kernel<<<blocks, TPB, 0, stream>>>(
        value, vel, P, obs, lm, mask, (float*)d_out, Bn);
}

// Round 5
// 185.065 us; speedup vs baseline: 1.2594x; 1.2594x over previous
//
#include <hip/hip_runtime.h>

#define NUM 16
#define TPB 256
#define TRK_PER_THREAD 2

// One thread per 2 adjacent (batch,track) pairs. No LDS, no barriers: all
// global loads for both tracks are issued up front (~11 outstanding vmem ops
// per thread) to maximize memory-level parallelism. Plain cached loads and
// stores — round 4 showed nontemporal hints cause 2x write amplification
// (partial-line eviction -> RMW) and defeat L3 input residency.
__global__ __launch_bounds__(TPB) void kf_update_kernel(
    const float* __restrict__ value,   // (B, 32)
    const float* __restrict__ vel,     // (B, 32)
    const float* __restrict__ Pin,     // (B, 16, 4, 4)
    const float* __restrict__ obs,     // (B, 32)
    const int*   __restrict__ lm,      // (B, 16)
    const int*   __restrict__ mask,    // (B, 16)
    float* __restrict__ out,           // rv(B*32) | rm(B*16) | rvel(B*32) | rP(B*256)
    int Bn)
{
    const int gtid  = blockIdx.x * TPB + threadIdx.x;  // pair index
    const int total = Bn * NUM;                        // track count
    if (gtid * TRK_PER_THREAD >= total) return;

    // ---- issue ALL loads up front ----
    const float4 vv = reinterpret_cast<const float4*>(value)[gtid]; // trk0:(x,y) trk1:(z,w)
    const float4 uu = reinterpret_cast<const float4*>(vel)[gtid];
    const float4 oo = reinterpret_cast<const float4*>(obs)[gtid];
    const int2   ll = reinterpret_cast<const int2*>(lm)[gtid];
    const int2   mm = reinterpret_cast<const int2*>(mask)[gtid];

    float Pm[TRK_PER_THREAD][16];
    {
        const float4* Pg = reinterpret_cast<const float4*>(Pin) + (size_t)gtid * 8;
        #pragma unroll
        for (int c = 0; c < 8; ++c) {
            const float4 x = Pg[c];
            Pm[c >> 2][(c & 3) * 4 + 0] = x.x;
            Pm[c >> 2][(c & 3) * 4 + 1] = x.y;
            Pm[c >> 2][(c & 3) * 4 + 2] = x.z;
            Pm[c >> 2][(c & 3) * 4 + 3] = x.w;
        }
    }

    float rv[TRK_PER_THREAD][2], rvl[TRK_PER_THREAD][2], rmv[TRK_PER_THREAD];
    float rP[TRK_PER_THREAD][16];

    #pragma unroll
    for (int t = 0; t < TRK_PER_THREAD; ++t) {
        const float vx = (t == 0) ? vv.x : vv.z;
        const float vy = (t == 0) ? vv.y : vv.w;
        const float ux = (t == 0) ? uu.x : uu.z;
        const float uy = (t == 0) ? uu.y : uu.w;
        const float ox = (t == 0) ? oo.x : oo.z;
        const float oy = (t == 0) ? oo.y : oo.w;
        const int   l  = (t == 0) ? ll.x : ll.y;
        const int   m  = (t == 0) ? mm.x : mm.y;
        const float* P = Pm[t];

        // predict
        const float p0 = vx + ux;
        const float p1 = vy + uy;
        const float p2 = ux;
        const float p3 = uy;

        // pP = F P F^T (row adds then col adds)
        float Q[4][4];
        #pragma unroll
        for (int j = 0; j < 4; ++j) {
            Q[0][j] = P[0 * 4 + j] + P[2 * 4 + j];
            Q[1][j] = P[1 * 4 + j] + P[3 * 4 + j];
            Q[2][j] = P[2 * 4 + j];
            Q[3][j] = P[3 * 4 + j];
        }
        float pP[4][4];
        #pragma unroll
        for (int i = 0; i < 4; ++i) {
            pP[i][0] = Q[i][0] + Q[i][2];
            pP[i][1] = Q[i][1] + Q[i][3];
            pP[i][2] = Q[i][2];
            pP[i][3] = Q[i][3];
        }

        // S = pP[:2,:2] + 1e-5 I; closed-form 2x2 inverse
        const float S00 = pP[0][0] + 1e-5f;
        const float S01 = pP[0][1];
        const float S10 = pP[1][0];
        const float S11 = pP[1][1] + 1e-5f;
        const float rdet = 1.0f / (S00 * S11 - S01 * S10);

        // K = pP[:, :2] @ Sinv
        float K0[4], K1[4];
        #pragma unroll
        for (int i = 0; i < 4; ++i) {
            K0[i] = (pP[i][0] * S11 - pP[i][1] * S10) * rdet;
            K1[i] = (pP[i][1] * S00 - pP[i][0] * S01) * rdet;
        }

        // state update
        const float y0 = ox - p0;
        const float y1 = oy - p1;
        const float upd0 = p0 + K0[0] * y0 + K1[0] * y1;
        const float upd1 = p1 + K0[1] * y0 + K1[1] * y1;
        const float upd2 = p2 + K0[2] * y0 + K1[2] * y1;
        const float upd3 = p3 + K0[3] * y0 + K1[3] * y1;

        // condition table
        const bool c1  = (l == 0) && (m == 0);
        const bool c2  = (l == 0) && (m != 0);
        const bool c3  = (l != 0) && (m == 0);
        const bool c4  = (l != 0) && (m != 0);
        const bool c3a = c3 && (l <= 5);

        rv[t][0]  = c4 ? upd0 : (c3 ? p0 : ox);
        rv[t][1]  = c4 ? upd1 : (c3 ? p1 : oy);
        rvl[t][0] = c4 ? upd2 : (c3a ? p2 : 0.0f);
        rvl[t][1] = c4 ? upd3 : (c3a ? p3 : 0.0f);
        rmv[t]    = (c2 || c4) ? 1.0f : (c3a ? (float)(l + 1) : 0.0f);

        // rP = select(c1: diag, c3a: pP, c4: pP - K pP[:2,:], else 0)
        #pragma unroll
        for (int i = 0; i < 4; ++i) {
            #pragma unroll
            for (int j = 0; j < 4; ++j) {
                const float Pn   = pP[i][j] - (K0[i] * pP[0][j] + K1[i] * pP[1][j]);
                const float diag = (i == j) ? ((i < 2) ? 1.0f : 10.0f) : 0.0f;
                rP[t][i * 4 + j] = c1 ? diag : (c3a ? pP[i][j] : (c4 ? Pn : 0.0f));
            }
        }
    }

    // ---- stores (plain cached; L2 merges the per-thread 128B runs) ----
    float* rv_out   = out;
    float* rm_out   = out + (size_t)Bn * 32;
    float* rvel_out = out + (size_t)Bn * 48;
    float* rP_out   = out + (size_t)Bn * 80;

    reinterpret_cast<float4*>(rv_out)[gtid] =
        make_float4(rv[0][0], rv[0][1], rv[1][0], rv[1][1]);
    reinterpret_cast<float2*>(rm_out)[gtid] = make_float2(rmv[0], rmv[1]);
    reinterpret_cast<float4*>(rvel_out)[gtid] =
        make_float4(rvl[0][0], rvl[0][1], rvl[1][0], rvl[1][1]);

    float4* rPg = reinterpret_cast<float4*>(rP_out) + (size_t)gtid * 8;
    #pragma unroll
    for (int c = 0; c < 8; ++c) {
        const float* s = &rP[c >> 2][(c & 3) * 4];
        rPg[c] = make_float4(s[0], s[1], s[2], s[3]);
    }
}

extern "C" void kernel_launch(void* const* d_in, const int* in_sizes, int n_in,
                              void* d_out, int out_size, void* d_ws, size_t ws_size,
                              hipStream_t stream) {
    const float* value = (const float*)d_in[0];
    const float* vel   = (const float*)d_in[1];
    const float* P     = (const float*)d_in[2];
    const float* obs   = (const float*)d_in[3];
    const int*   lm    = (const int*)d_in[4];
    const int*   mask  = (const int*)d_in[5];

    const int Bn    = in_sizes[0] / (2 * NUM);   // value is (B, 2*NUM)
    const int total = Bn * NUM;
    const int pairs = (total + TRK_PER_THREAD - 1) / TRK_PER_THREAD;
    const int blocks = (pairs + TPB - 1) / TPB;

    kf_update_kernel<<<blocks, TPB, 0, stream>>>(
        value, vel, P, obs, lm, mask, (float*)d_out, Bn);
}

// Round 6
// 180.654 us; speedup vs baseline: 1.2902x; 1.0244x over previous
//
#include <hip/hip_runtime.h>

#define NUM 16
#define TPB 256
#define TILES 4          // tiles (of TPB tracks) per block
#define PSTRIDE 20       // LDS floats/track: 16 data + 4 pad (16B-aligned, <=2-way banks)

// Software-pipelined persistent-style kernel: each block processes TILES
// tiles of 256 tracks with double-buffered LDS staging of P. Global prefetch
// of tile i+1 is issued before compute/store of tile i, so load and store
// traffic overlap continuously (one barrier per tile). Stores are direct
// from registers (store-side LDS staging measured neutral in r1 vs r2).
__global__ __launch_bounds__(TPB) void kf_update_kernel(
    const float* __restrict__ value,   // (B, 32)
    const float* __restrict__ vel,     // (B, 32)
    const float* __restrict__ Pin,     // (B, 16, 4, 4)
    const float* __restrict__ obs,     // (B, 32)
    const int*   __restrict__ lm,      // (B, 16)
    const int*   __restrict__ mask,    // (B, 16)
    float* __restrict__ out,           // rv(B*32) | rm(B*16) | rvel(B*32) | rP(B*256)
    int Bn)
{
    __shared__ float sm[2][TPB * PSTRIDE];   // 2 x 20 KB -> 4 blocks/CU

    const int tid   = threadIdx.x;
    const int total = Bn * NUM;
    const int tile0 = blockIdx.x * TILES;

    float* rv_out   = out;
    float* rm_out   = out + (size_t)Bn * 32;
    float* rvel_out = out + (size_t)Bn * 48;
    float* rP_out   = out + (size_t)Bn * 80;

    // prefetch registers
    float4 g[4];                       // staging chunks (lane-contiguous, others' data)
    float2 pv = make_float2(0.f,0.f), pu = pv, po = pv;
    int    pl = 0, pm_ = 0;

    // ---- prefetch tile 0 ----
    {
        const long long base = (long long)tile0 * TPB;          // first track
        const long long lim4 = (long long)total * 4 - base * 4; // float4 bound
        const float4* Pg = reinterpret_cast<const float4*>(Pin) + base * 4;
        #pragma unroll
        for (int k = 0; k < 4; ++k)
            g[k] = (tid + TPB * k < lim4) ? Pg[tid + TPB * k]
                                          : make_float4(0.f,0.f,0.f,0.f);
        const long long t = base + tid;
        if (t < total) {
            pv  = reinterpret_cast<const float2*>(value)[t];
            pu  = reinterpret_cast<const float2*>(vel)[t];
            po  = reinterpret_cast<const float2*>(obs)[t];
            pl  = lm[t];
            pm_ = mask[t];
        }
    }
    // stage into buffer 0
    #pragma unroll
    for (int k = 0; k < 4; ++k) {
        const int gi = tid + TPB * k, tr = gi >> 2, part = gi & 3;
        *reinterpret_cast<float4*>(&sm[0][tr * PSTRIDE + part * 4]) = g[k];
    }
    __syncthreads();

    for (int it = 0; it < TILES; ++it) {
        const int cur = it & 1, nxt = cur ^ 1;
        const long long base  = (long long)(tile0 + it) * TPB;
        const long long track = base + tid;
        const bool active = track < total;

        // capture current tile's per-track inputs
        const float2 v = pv, u = pu, o = po;
        const int l = pl, m = pm_;

        // ---- issue global prefetch for tile it+1 (overlaps compute/store) ----
        const bool havenext = (it + 1 < TILES) &&
                              ((long long)(tile0 + it + 1) * TPB < total);
        if (havenext) {
            const long long nb   = (long long)(tile0 + it + 1) * TPB;
            const long long lim4 = (long long)total * 4 - nb * 4;
            const float4* Pg = reinterpret_cast<const float4*>(Pin) + nb * 4;
            #pragma unroll
            for (int k = 0; k < 4; ++k)
                g[k] = (tid + TPB * k < lim4) ? Pg[tid + TPB * k]
                                              : make_float4(0.f,0.f,0.f,0.f);
            const long long nt = nb + tid;
            if (nt < total) {
                pv  = reinterpret_cast<const float2*>(value)[nt];
                pu  = reinterpret_cast<const float2*>(vel)[nt];
                po  = reinterpret_cast<const float2*>(obs)[nt];
                pl  = lm[nt];
                pm_ = mask[nt];
            }
        }

        // ---- read own P from LDS (ds_read_b128, padded stride) ----
        float Pm[16];
        #pragma unroll
        for (int c = 0; c < 4; ++c) {
            const float4 x = *reinterpret_cast<const float4*>(
                &sm[cur][tid * PSTRIDE + c * 4]);
            Pm[c*4+0] = x.x; Pm[c*4+1] = x.y; Pm[c*4+2] = x.z; Pm[c*4+3] = x.w;
        }

        // ---- predict ----
        const float p0 = v.x + u.x;
        const float p1 = v.y + u.y;
        const float p2 = u.x;
        const float p3 = u.y;

        // ---- pP = F P F^T (row adds then col adds) ----
        float Q[4][4];
        #pragma unroll
        for (int j = 0; j < 4; ++j) {
            Q[0][j] = Pm[0*4+j] + Pm[2*4+j];
            Q[1][j] = Pm[1*4+j] + Pm[3*4+j];
            Q[2][j] = Pm[2*4+j];
            Q[3][j] = Pm[3*4+j];
        }
        float pP[4][4];
        #pragma unroll
        for (int i = 0; i < 4; ++i) {
            pP[i][0] = Q[i][0] + Q[i][2];
            pP[i][1] = Q[i][1] + Q[i][3];
            pP[i][2] = Q[i][2];
            pP[i][3] = Q[i][3];
        }

        // ---- S = pP[:2,:2] + 1e-5 I; closed-form 2x2 inverse ----
        const float S00 = pP[0][0] + 1e-5f;
        const float S01 = pP[0][1];
        const float S10 = pP[1][0];
        const float S11 = pP[1][1] + 1e-5f;
        const float rdet = 1.0f / (S00 * S11 - S01 * S10);

        // ---- K = pP[:, :2] @ Sinv ----
        float K0[4], K1[4];
        #pragma unroll
        for (int i = 0; i < 4; ++i) {
            K0[i] = (pP[i][0] * S11 - pP[i][1] * S10) * rdet;
            K1[i] = (pP[i][1] * S00 - pP[i][0] * S01) * rdet;
        }

        // ---- state update ----
        const float y0 = o.x - p0;
        const float y1 = o.y - p1;
        const float upd0 = p0 + K0[0]*y0 + K1[0]*y1;
        const float upd1 = p1 + K0[1]*y0 + K1[1]*y1;
        const float upd2 = p2 + K0[2]*y0 + K1[2]*y1;
        const float upd3 = p3 + K0[3]*y0 + K1[3]*y1;

        // ---- condition table ----
        const bool c1  = (l == 0) && (m == 0);
        const bool c2  = (l == 0) && (m != 0);
        const bool c3  = (l != 0) && (m == 0);
        const bool c4  = (l != 0) && (m != 0);
        const bool c3a = c3 && (l <= 5);

        const float rv0  = c4 ? upd0 : (c3 ? p0 : o.x);
        const float rv1  = c4 ? upd1 : (c3 ? p1 : o.y);
        const float rvl0 = c4 ? upd2 : (c3a ? p2 : 0.0f);
        const float rvl1 = c4 ? upd3 : (c3a ? p3 : 0.0f);
        const float rmv  = (c2 || c4) ? 1.0f : (c3a ? (float)(l + 1) : 0.0f);

        // ---- stores (direct; L2 merges) ----
        if (active) {
            reinterpret_cast<float2*>(rv_out)[track]   = make_float2(rv0, rv1);
            rm_out[track] = rmv;
            reinterpret_cast<float2*>(rvel_out)[track] = make_float2(rvl0, rvl1);

            float4* rPg = reinterpret_cast<float4*>(rP_out) + track * 4;
            #pragma unroll
            for (int i = 0; i < 4; ++i) {
                float e[4];
                #pragma unroll
                for (int j = 0; j < 4; ++j) {
                    const float Pn   = pP[i][j] - (K0[i]*pP[0][j] + K1[i]*pP[1][j]);
                    const float diag = (i == j) ? ((i < 2) ? 1.0f : 10.0f) : 0.0f;
                    e[j] = c1 ? diag : (c3a ? pP[i][j] : (c4 ? Pn : 0.0f));
                }
                rPg[i] = make_float4(e[0], e[1], e[2], e[3]);
            }
        }

        // ---- stage prefetched tile into the other buffer, one barrier ----
        if (havenext) {
            #pragma unroll
            for (int k = 0; k < 4; ++k) {
                const int gi = tid + TPB * k, tr = gi >> 2, part = gi & 3;
                *reinterpret_cast<float4*>(&sm[nxt][tr * PSTRIDE + part * 4]) = g[k];
            }
            __syncthreads();
        }
    }
}

extern "C" void kernel_launch(void* const* d_in, const int* in_sizes, int n_in,
                              void* d_out, int out_size, void* d_ws, size_t ws_size,
                              hipStream_t stream) {
    const float* value = (const float*)d_in[0];
    const float* vel   = (const float*)d_in[1];
    const float* P     = (const float*)d_in[2];
    const float* obs   = (const float*)d_in[3];
    const int*   lm    = (const int*)d_in[4];
    const int*   mask  = (const int*)d_in[5];

    const int Bn    = in_sizes[0] / (2 * NUM);   // value is (B, 2*NUM)
    const int total = Bn * NUM;
    const int blocks = (total + TPB * TILES - 1) / (TPB * TILES);  // 1024 for B=65536

    kf_update_kernel<<<blocks, TPB, 0, stream>>>(
        value, vel, P, obs, lm, mask, (float*)d_out, Bn);
}

// Round 7
// 176.961 us; speedup vs baseline: 1.3171x; 1.0209x over previous
//
#include <hip/hip_runtime.h>

#define NUM 16
#define TPB 256
// LDS floats per track: 16 data + 4 pad. Keeps every float4 chunk 16B-aligned
// (80 B stride) and breaks the 64-B bank aliasing.
#define PSTRIDE 20

// FINAL (= round-2 best: 57.6-58.5 us kernel, ~2.4 TB/s TCC bandwidth).
// One thread per (batch, track). P / rP staged through LDS so every global
// memory instruction is lane-contiguous (1 KB per wave per instruction).
// Verdict from rounds 1-6: five structural variants (strided-direct, this,
// nontemporal, 2-track/thread, double-buffered pipeline) all pin at
// ~2.4 TB/s for this 36/64 read/write mix; traffic is minimal (FETCH 49 MB
// after L3 absorption, WRITE 86 MB mandatory) -> memory-bound roofline.
__global__ __launch_bounds__(TPB) void kf_update_kernel(
    const float* __restrict__ value,   // (B, 32)
    const float* __restrict__ vel,     // (B, 32)
    const float* __restrict__ Pin,     // (B, 16, 4, 4)
    const float* __restrict__ obs,     // (B, 32)
    const int*   __restrict__ lm,      // (B, 16)
    const int*   __restrict__ mask,    // (B, 16)
    float* __restrict__ out,           // rv(B*32) | rm(B*16) | rvel(B*32) | rP(B*256)
    int Bn)
{
    __shared__ float sm[TPB * PSTRIDE];   // 20 KB -> 8 blocks/CU

    const int tid   = threadIdx.x;
    const int gtid  = blockIdx.x * TPB + tid;
    const int total = Bn * NUM;
    const long long blockBase = (long long)blockIdx.x * TPB;  // first track of block
    const bool active = gtid < total;

    // ---- stage P: contiguous global float4 loads -> padded LDS ----
    {
        const float4* Pg = reinterpret_cast<const float4*>(Pin) + blockBase * 4;
        const long long limit = (long long)total * 4 - blockBase * 4;
        #pragma unroll
        for (int k = 0; k < 4; ++k) {
            const int g = tid + TPB * k;          // float4 index within block tile
            if (g < limit) {
                const float4 x = Pg[g];
                const int tr = g >> 2, part = g & 3;
                *reinterpret_cast<float4*>(&sm[tr * PSTRIDE + part * 4]) = x;
            }
        }
    }

    // ---- scalar per-track loads (coalesced already) ----
    float2 v = make_float2(0.f, 0.f), u = v, o = v;
    int l = 0, m = 0;
    if (active) {
        v = reinterpret_cast<const float2*>(value)[gtid];
        u = reinterpret_cast<const float2*>(vel)[gtid];
        o = reinterpret_cast<const float2*>(obs)[gtid];
        l = lm[gtid];
        m = mask[gtid];
    }

    __syncthreads();

    // ---- read own track's P from LDS (ds_read_b128) ----
    float Pm[16];
    #pragma unroll
    for (int c = 0; c < 4; ++c) {
        const float4 x = *reinterpret_cast<const float4*>(&sm[tid * PSTRIDE + c * 4]);
        Pm[c * 4 + 0] = x.x; Pm[c * 4 + 1] = x.y;
        Pm[c * 4 + 2] = x.z; Pm[c * 4 + 3] = x.w;
    }

    // ---- predict: pred = F @ [vx,vy,ux,uy] ----
    const float p0 = v.x + u.x;
    const float p1 = v.y + u.y;
    const float p2 = u.x;
    const float p3 = u.y;

    // ---- pP = F P F^T: row adds then col adds ----
    float Q[4][4];
    #pragma unroll
    for (int j = 0; j < 4; ++j) {
        Q[0][j] = Pm[0 * 4 + j] + Pm[2 * 4 + j];
        Q[1][j] = Pm[1 * 4 + j] + Pm[3 * 4 + j];
        Q[2][j] = Pm[2 * 4 + j];
        Q[3][j] = Pm[3 * 4 + j];
    }
    float pP[4][4];
    #pragma unroll
    for (int i = 0; i < 4; ++i) {
        pP[i][0] = Q[i][0] + Q[i][2];
        pP[i][1] = Q[i][1] + Q[i][3];
        pP[i][2] = Q[i][2];
        pP[i][3] = Q[i][3];
    }

    // ---- S = pP[:2,:2] + 1e-5 I, closed-form 2x2 inverse ----
    const float S00 = pP[0][0] + 1e-5f;
    const float S01 = pP[0][1];
    const float S10 = pP[1][0];
    const float S11 = pP[1][1] + 1e-5f;
    const float det  = S00 * S11 - S01 * S10;
    const float rdet = 1.0f / det;

    // ---- K = pP[:, :2] @ Sinv ----
    float K0[4], K1[4];
    #pragma unroll
    for (int i = 0; i < 4; ++i) {
        K0[i] = (pP[i][0] * S11 - pP[i][1] * S10) * rdet;
        K1[i] = (pP[i][1] * S00 - pP[i][0] * S01) * rdet;
    }

    // ---- state update ----
    const float y0 = o.x - p0;
    const float y1 = o.y - p1;
    const float upd0 = p0 + K0[0] * y0 + K1[0] * y1;
    const float upd1 = p1 + K0[1] * y0 + K1[1] * y1;
    const float upd2 = p2 + K0[2] * y0 + K1[2] * y1;
    const float upd3 = p3 + K0[3] * y0 + K1[3] * y1;

    // ---- Pn = pP - K @ pP[:2, :] ----
    float Pn[4][4];
    #pragma unroll
    for (int i = 0; i < 4; ++i) {
        #pragma unroll
        for (int j = 0; j < 4; ++j) {
            Pn[i][j] = pP[i][j] - (K0[i] * pP[0][j] + K1[i] * pP[1][j]);
        }
    }

    // ---- condition table ----
    const bool c1  = (l == 0) && (m == 0);
    const bool c2  = (l == 0) && (m != 0);
    const bool c3  = (l != 0) && (m == 0);
    const bool c4  = (l != 0) && (m != 0);
    const bool c3a = c3 && (l <= 5);

    const float rv0  = c4 ? upd0 : (c3 ? p0 : o.x);
    const float rv1  = c4 ? upd1 : (c3 ? p1 : o.y);
    const float rvl0 = c4 ? upd2 : (c3a ? p2 : 0.0f);
    const float rvl1 = c4 ? upd3 : (c3a ? p3 : 0.0f);
    const float rmv  = (c2 || c4) ? 1.0f : (c3a ? (float)(l + 1) : 0.0f);

    // ---- small outputs (already coalesced) ----
    float* rv_out   = out;
    float* rm_out   = out + (size_t)Bn * 32;
    float* rvel_out = out + (size_t)Bn * 48;
    float* rP_out   = out + (size_t)Bn * 80;

    if (active) {
        reinterpret_cast<float2*>(rv_out)[gtid]   = make_float2(rv0, rv1);
        rm_out[gtid] = rmv;
        reinterpret_cast<float2*>(rvel_out)[gtid] = make_float2(rvl0, rvl1);
    }

    __syncthreads();   // everyone done reading P tile; reuse sm for rP

    // ---- write own rP rows into LDS ----
    #pragma unroll
    for (int i = 0; i < 4; ++i) {
        float e[4];
        #pragma unroll
        for (int j = 0; j < 4; ++j) {
            const float diag = (i == j) ? ((i < 2) ? 1.0f : 10.0f) : 0.0f;
            e[j] = c1 ? diag : (c3a ? pP[i][j] : (c4 ? Pn[i][j] : 0.0f));
        }
        *reinterpret_cast<float4*>(&sm[tid * PSTRIDE + i * 4]) =
            make_float4(e[0], e[1], e[2], e[3]);
    }

    __syncthreads();

    // ---- drain rP tile: padded LDS -> contiguous global float4 stores ----
    {
        float4* rPg = reinterpret_cast<float4*>(rP_out) + blockBase * 4;
        const long long limit = (long long)total * 4 - blockBase * 4;
        #pragma unroll
        for (int k = 0; k < 4; ++k) {
            const int g = tid + TPB * k;
            if (g < limit) {
                const int tr = g >> 2, part = g & 3;
                rPg[g] = *reinterpret_cast<const float4*>(&sm[tr * PSTRIDE + part * 4]);
            }
        }
    }
}

extern "C" void kernel_launch(void* const* d_in, const int* in_sizes, int n_in,
                              void* d_out, int out_size, void* d_ws, size_t ws_size,
                              hipStream_t stream) {
    const float* value = (const float*)d_in[0];
    const float* vel   = (const float*)d_in[1];
    const float* P     = (const float*)d_in[2];
    const float* obs   = (const float*)d_in[3];
    const int*   lm    = (const int*)d_in[4];
    const int*   mask  = (const int*)d_in[5];

    const int Bn    = in_sizes[0] / (2 * NUM);   // value is (B, 2*NUM)
    const int total = Bn * NUM;
    const int blocks = (total + TPB - 1) / TPB;

    kf_update_kernel<<<blocks, TPB, 0, stream>>>(
        value, vel, P, obs, lm, mask, (float*)d_out, Bn);
}